// Round 6
// baseline (19.591 us; speedup 1.0000x reference)
//
#include <hip/hip_runtime.h>

// MetaSR scale-4, 64x64x64 feat -> 3x256x256. Exact-in-fp32: iy=y>>2,
// rel0=(y&3)*0.25, rel1=(x&3)*0.25, r_rev=0.25 -> 16 distinct MLP inputs.
// Stage 1: predw[sg][ct][12]  (ct = c*9+tap, col j = (s&3)*3 + rgb).
// Stage 2: split-K conv. Block = (sg, 4-row group, 16-ch quarter); thread
//   owns 4 rows x 12 outputs (48 acc) so each weight-float4 LDS read feeds
//   16 FMAs (was 4). Per-CU ds_read_b128: 1728 -> 432. Partials in bf16.
// Stage 3: deterministic 4-way partial sum.

#define NOUT 1728

__device__ inline unsigned bf16pack(float a, float b) {
    unsigned ua = __builtin_bit_cast(unsigned, a);
    unsigned ub = __builtin_bit_cast(unsigned, b);
    ua = (ua + 0x7FFFu + ((ua >> 16) & 1u)) >> 16;
    ub = (ub + 0x7FFFu + ((ub >> 16) & 1u)) >> 16;
    return ua | (ub << 16);
}
__device__ inline float bf16lo(unsigned v) {
    return __builtin_bit_cast(float, v << 16);
}
__device__ inline float bf16hi(unsigned v) {
    return __builtin_bit_cast(float, v & 0xFFFF0000u);
}

// ---------------- Kernel 1: predw[4][576][12] ------------------------------
// grid 432 = 16 s * 27 chunks of 64 outputs; block 256 = 64 outputs * 4 Ksplit
__global__ __launch_bounds__(256) void k_predw(
    const float* __restrict__ w1, const float* __restrict__ b1,
    const float* __restrict__ w2, const float* __restrict__ b2,
    float* __restrict__ predw)
{
    __shared__ float h[256];
    __shared__ float red[256];
    const int tid   = threadIdx.x;
    const int s     = blockIdx.x / 27;
    const int chunk = blockIdx.x - s * 27;

    const float rel0 = (float)(s >> 2) * 0.25f;
    const float rel1 = (float)(s & 3) * 0.25f;

    float pre = fmaf(w1[tid], rel0,
                fmaf(w1[256 + tid], rel1,
                fmaf(w1[512 + tid], 0.25f, b1[tid])));
    h[tid] = fmaxf(pre, 0.0f);
    __syncthreads();

    const int olocal = tid & 63;
    const int q      = tid >> 6;           // K-quarter
    const int o      = chunk * 64 + olocal;
    const float* w2c = w2 + q * 64 * NOUT + o;
    const float* hq  = h + q * 64;

    float acc = 0.0f;
    #pragma unroll 8
    for (int j = 0; j < 64; ++j)
        acc = fmaf(hq[j], w2c[j * NOUT], acc);
    red[tid] = acc;
    __syncthreads();

    if (tid < 64) {
        const int oo = chunk * 64 + tid;   // oo = ct*3 + k
        float a = red[tid] + red[tid + 64] + red[tid + 128] + red[tid + 192]
                + b2[oo];
        const int ct = oo / 3;
        const int k  = oo - ct * 3;
        predw[((s >> 2) * 576 + ct) * 12 + (s & 3) * 3 + k] = a;
    }
}

// ---------------- Kernel 2: split-K conv partials --------------------------
// grid 256 = 4 sg * 16 rowgroups * 4 chq; block 256 = 4 waves * 4 ch each
__global__ __launch_bounds__(256) void k_conv_part(
    const float* __restrict__ feat, const float* __restrict__ predw,
    unsigned short* __restrict__ part)
{
    __shared__ float pw[1728];             // 16 ch * 108
    __shared__ float red[2 * 48 * 64];     // 24 KB reduce buffer

    const int tid  = threadIdx.x;
    const int bid  = blockIdx.x;
    const int chq  = bid & 3;
    const int rg   = (bid >> 2) & 15;
    const int sg   = bid >> 6;
    const int lane = tid & 63;             // x
    const int wq   = __builtin_amdgcn_readfirstlane(tid >> 6);  // 0..3

    // stage pw slice: 432 float4, coalesced
    {
        const float4* src = (const float4*)(predw + sg * 6912 + chq * 1728);
        float4* dst = (float4*)pw;
        dst[tid] = src[tid];
        if (tid < 176) dst[tid + 256] = src[tid + 256];
    }

    // x offsets/masks
    int xoff[3]; float xm[3];
    #pragma unroll
    for (int tc = 0; tc < 3; ++tc) {
        const int rx = lane + tc - 1;
        xm[tc] = ((unsigned)rx < 64u) ? 1.0f : 0.0f;
        xoff[tc] = rx < 0 ? 0 : (rx > 63 ? 63 : rx);
    }
    // y offsets + combined masks for rows rbase-1 .. rbase+4
    const int rbase = rg << 2;
    int yoff[6]; float mm[6][3];
    #pragma unroll
    for (int rr = 0; rr < 6; ++rr) {
        const int ry = rbase + rr - 1;
        const float ym = ((unsigned)ry < 64u) ? 1.0f : 0.0f;
        const int cry = ry < 0 ? 0 : (ry > 63 ? 63 : ry);
        yoff[rr] = cry << 6;
        #pragma unroll
        for (int tc = 0; tc < 3; ++tc) mm[rr][tc] = ym * xm[tc];
    }
    __syncthreads();

    float acc[4][12];
    #pragma unroll
    for (int ri = 0; ri < 4; ++ri)
        #pragma unroll
        for (int j = 0; j < 12; ++j) acc[ri][j] = 0.0f;

    #pragma unroll
    for (int cc = 0; cc < 4; ++cc) {
        const int lc = (wq << 2) | cc;         // local channel 0..15
        const int c  = (chq << 4) | lc;        // global channel
        const float* fc = feat + (c << 12);

        float f[6][3];
        #pragma unroll
        for (int rr = 0; rr < 6; ++rr)
            #pragma unroll
            for (int tc = 0; tc < 3; ++tc)
                f[rr][tc] = fc[yoff[rr] + xoff[tc]] * mm[rr][tc];

        const float4* pwc = (const float4*)pw + lc * 27;   // wave-uniform
        #pragma unroll
        for (int tr = 0; tr < 3; ++tr) {
            #pragma unroll
            for (int tc = 0; tc < 3; ++tc) {
                const int tap = tr * 3 + tc;
                const float4 wA = pwc[tap * 3 + 0];
                const float4 wB = pwc[tap * 3 + 1];
                const float4 wC = pwc[tap * 3 + 2];
                #pragma unroll
                for (int ri = 0; ri < 4; ++ri) {
                    const float v = f[ri + tr][tc];
                    acc[ri][0]  = fmaf(v, wA.x, acc[ri][0]);
                    acc[ri][1]  = fmaf(v, wA.y, acc[ri][1]);
                    acc[ri][2]  = fmaf(v, wA.z, acc[ri][2]);
                    acc[ri][3]  = fmaf(v, wA.w, acc[ri][3]);
                    acc[ri][4]  = fmaf(v, wB.x, acc[ri][4]);
                    acc[ri][5]  = fmaf(v, wB.y, acc[ri][5]);
                    acc[ri][6]  = fmaf(v, wB.z, acc[ri][6]);
                    acc[ri][7]  = fmaf(v, wB.w, acc[ri][7]);
                    acc[ri][8]  = fmaf(v, wC.x, acc[ri][8]);
                    acc[ri][9]  = fmaf(v, wC.y, acc[ri][9]);
                    acc[ri][10] = fmaf(v, wC.z, acc[ri][10]);
                    acc[ri][11] = fmaf(v, wC.w, acc[ri][11]);
                }
            }
        }
    }

    // tree reduce 4 waves -> wave 0
    for (int half = 2; half >= 1; half >>= 1) {
        if (wq >= half && wq < 2 * half) {
            #pragma unroll
            for (int ri = 0; ri < 4; ++ri)
                #pragma unroll
                for (int j = 0; j < 12; ++j)
                    red[((wq - half) * 48 + ri * 12 + j) * 64 + lane] = acc[ri][j];
        }
        __syncthreads();
        if (wq < half) {
            #pragma unroll
            for (int ri = 0; ri < 4; ++ri)
                #pragma unroll
                for (int j = 0; j < 12; ++j)
                    acc[ri][j] += red[(wq * 48 + ri * 12 + j) * 64 + lane];
        }
        __syncthreads();
    }

    // wave0 -> LDS transpose buffer
    if (wq == 0) {
        #pragma unroll
        for (int ri = 0; ri < 4; ++ri)
            #pragma unroll
            for (int j = 0; j < 12; ++j)
                red[(ri * 12 + j) * 64 + lane] = acc[ri][j];
    }
    __syncthreads();

    // coalesced bf16 partial stores: 3 quads (8B) per thread
    #pragma unroll
    for (int e = 0; e < 3; ++e) {
        const int u   = e * 256 + tid;     // 0..767
        const int x4  = u & 63;
        const int rem = u >> 6;            // 0..11
        const int k   = rem % 3;
        const int ri  = rem / 3;
        const float v0 = red[(ri * 12 + 0 * 3 + k) * 64 + x4];
        const float v1 = red[(ri * 12 + 1 * 3 + k) * 64 + x4];
        const float v2 = red[(ri * 12 + 2 * 3 + k) * 64 + x4];
        const float v3 = red[(ri * 12 + 3 * 3 + k) * 64 + x4];
        const int y = ((rbase + ri) << 2) + sg;
        unsigned short* p = part + chq * 196608 + k * 65536 + y * 256 + (x4 << 2);
        uint2 v; v.x = bf16pack(v0, v1); v.y = bf16pack(v2, v3);
        *(uint2*)p = v;
    }
}

// ---------------- Kernel 3: deterministic partial sum ----------------------
// grid 192 * 256: one float4 output per thread
__global__ __launch_bounds__(256) void k_combine(
    const unsigned short* __restrict__ part, float* __restrict__ out)
{
    const int g = blockIdx.x * 256 + threadIdx.x;     // 0..49151
    const uint2* p = (const uint2*)part;
    float4 s = make_float4(0.f, 0.f, 0.f, 0.f);
    #pragma unroll
    for (int q = 0; q < 4; ++q) {
        const uint2 v = p[q * 49152 + g];
        s.x += bf16lo(v.x);
        s.y += bf16hi(v.x);
        s.z += bf16lo(v.y);
        s.w += bf16hi(v.y);
    }
    ((float4*)out)[g] = s;
}

extern "C" void kernel_launch(void* const* d_in, const int* in_sizes, int n_in,
                              void* d_out, int out_size, void* d_ws, size_t ws_size,
                              hipStream_t stream) {
    const float* feat = (const float*)d_in[0];
    const float* w1   = (const float*)d_in[1];
    const float* b1   = (const float*)d_in[2];
    const float* w2   = (const float*)d_in[3];
    const float* b2   = (const float*)d_in[4];
    float* out   = (float*)d_out;
    float* predw = (float*)d_ws;                       // 27648 floats
    unsigned short* part =
        (unsigned short*)((char*)d_ws + 110592);       // 786432 bf16 = 1.5 MB

    hipLaunchKernelGGL(k_predw, dim3(432), dim3(256), 0, stream,
                       w1, b1, w2, b2, predw);
    hipLaunchKernelGGL(k_conv_part, dim3(256), dim3(256), 0, stream,
                       feat, predw, part);
    hipLaunchKernelGGL(k_combine, dim3(192), dim3(256), 0, stream,
                       part, out);
}